// Round 13
// baseline (613.074 us; speedup 1.0000x reference)
//
#include <hip/hip_runtime.h>
#include <hip/hip_bf16.h>

// Multi-relational GCN, 4 layers. Round 13:
//  - XCD-sliced SpMM: XW split into 8 slices [q=(js,i,half)][N][32] bf16,
//    3.2MB each; q = bid&7 -> one slice per XCD's L2 (round-robin dispatch).
//    js=0 waves write out (f32), js=1 waves write partial P (bf16);
//    sum+relu deferred into next gemm's A-load; k_addP after layer 4.
//  - MFMA gemm (epilogue stores slice layout), r12 build/fill unchanged.
//  - Fallback (small ws): whole-row spmm on the same slice layout, no P.
// relation r = 2*i + j: dst type i = r>>1, src type j = r&1.
// Segments 0..3 = adj1 (layers 1-2), 4..7 = adj2 (layers 3-4).

#define DOUT 64
#define WBINS 12800   // 51.2 KB LDS histogram window / fill row-window
#define CCH   8       // edge chunks

typedef __attribute__((ext_vector_type(8))) short s16x8;
typedef __attribute__((ext_vector_type(4))) float f32x4;

__device__ __forceinline__ float bf2f_lo(unsigned u) {
    return __uint_as_float(u << 16);
}
__device__ __forceinline__ float bf2f_hi(unsigned u) {
    return __uint_as_float(u & 0xffff0000u);
}
__device__ __forceinline__ unsigned short f2bf(float x) {
    union { __hip_bfloat16 h; unsigned short s; } u;
    u.h = __float2bfloat16(x);
    return u.s;
}

// ---------------- build: per-(seg,window,chunk) LDS histogram + u16 rank
__global__ __launch_bounds__(1024) void k_build(
    const int* __restrict__ rows1, const int* __restrict__ rows2,
    int E, int chunkE, int N, int* __restrict__ cnt3, unsigned short* __restrict__ rank)
{
    __shared__ int bins[WBINS];
    const int w = blockIdx.x;
    const int s = blockIdx.y;
    const int c = blockIdx.z;
    const int lo = w * WBINS;
    const int hi = min(N, lo + WBINS);
    const int nb = hi - lo;
    if (nb <= 0) return;
    const int* rows = (s < 4) ? rows1 : rows2;
    const size_t base = (size_t)(s & 3) * E;
    const int e0 = c * chunkE;
    const int e1 = min(E, e0 + chunkE);

    for (int b = threadIdx.x; b < nb; b += 1024) bins[b] = 0;
    __syncthreads();

    for (int e = e0 + threadIdx.x; e < e1; e += 1024) {
        const int row = rows[base + e];
        if (row >= lo && row < hi) {
            const int r = atomicAdd(&bins[row - lo], 1);
            rank[(size_t)s * E + e] = (unsigned short)r;
        }
    }
    __syncthreads();

    for (int b = threadIdx.x; b < nb; b += 1024)
        cnt3[((size_t)(s * CCH + c)) * N + lo + b] = bins[b];
}

// ---------------- per-row: exclusive prefix over chunk counts (in place) + total
__global__ __launch_bounds__(256) void k_rowsum(
    int* __restrict__ cnt3, int* __restrict__ cnt, int N)
{
    const int row = blockIdx.x * 256 + threadIdx.x;
    const int s   = blockIdx.y;
    if (row >= N) return;
    int sum = 0;
#pragma unroll
    for (int c = 0; c < CCH; ++c) {
        const size_t idx = ((size_t)(s * CCH + c)) * N + row;
        const int v = cnt3[idx];
        cnt3[idx] = sum;
        sum += v;
    }
    cnt[(size_t)s * N + row] = sum;
}

// ---------------- exclusive scan, 3-kernel
__global__ __launch_bounds__(256) void k_scan1(
    const int* __restrict__ cnt, int M, int* __restrict__ out, int* __restrict__ partials)
{
    __shared__ int sm[256];
    const int i = blockIdx.x * 256 + threadIdx.x;
    const int x = (i < M) ? cnt[i] : 0;
    sm[threadIdx.x] = x;
    __syncthreads();
    for (int off = 1; off < 256; off <<= 1) {
        int t = (threadIdx.x >= off) ? sm[threadIdx.x - off] : 0;
        __syncthreads();
        sm[threadIdx.x] += t;
        __syncthreads();
    }
    if (i < M) out[i] = sm[threadIdx.x] - x;
    if (threadIdx.x == 255) partials[blockIdx.x] = sm[255];
}

__global__ __launch_bounds__(256) void k_scan2(int* __restrict__ partials, int nb)
{
    __shared__ int sm[256];
    __shared__ int carry_s;
    if (threadIdx.x == 0) carry_s = 0;
    __syncthreads();
    for (int base = 0; base < nb; base += 256) {
        const int i = base + threadIdx.x;
        const int x = (i < nb) ? partials[i] : 0;
        sm[threadIdx.x] = x;
        __syncthreads();
        for (int off = 1; off < 256; off <<= 1) {
            int t = (threadIdx.x >= off) ? sm[threadIdx.x - off] : 0;
            __syncthreads();
            sm[threadIdx.x] += t;
            __syncthreads();
        }
        const int carry = carry_s;
        const int incl  = sm[threadIdx.x];
        __syncthreads();
        if (i < nb) partials[i] = incl - x + carry;
        if (threadIdx.x == 255) carry_s = carry + incl;
        __syncthreads();
    }
}

__global__ __launch_bounds__(256) void k_scan3(
    int* __restrict__ row_ptr, const int* __restrict__ partials, int M, int total)
{
    const int i = blockIdx.x * 256 + threadIdx.x;
    if (i < M) row_ptr[i] += partials[blockIdx.x];
    if (i == 0) row_ptr[M] = total;
}

// ---------------- base fusion: cnt3[(s,c),row] += row_ptr[s,row]  (in place)
__global__ __launch_bounds__(256) void k_base(
    int* __restrict__ cnt3, const int* __restrict__ row_ptr, int N)
{
    const int row = blockIdx.x * 256 + threadIdx.x;
    const int s   = blockIdx.y;
    const int c   = blockIdx.z;
    if (row >= N) return;
    cnt3[((size_t)(s * CCH + c)) * N + row] += row_ptr[(size_t)s * N + row];
}

// ---------------- row-windowed atomic-free CSR fill: pos = base3 + rank
__global__ __launch_bounds__(256) void k_fill(
    const int* __restrict__ rows1, const int* __restrict__ cols1, const float* __restrict__ vals1,
    const int* __restrict__ rows2, const int* __restrict__ cols2, const float* __restrict__ vals2,
    int E, int chunkE, int N,
    const int* __restrict__ base3, const unsigned short* __restrict__ rank,
    int2* __restrict__ cv)
{
    const int s  = blockIdx.x;
    const int z  = blockIdx.z;
    const int c  = z % CCH;
    const int wf = z / CCH;
    const int lo = wf * WBINS;
    const int hi = min(N, lo + WBINS);
    const int el = blockIdx.y * 256 + threadIdx.x;
    const int e  = c * chunkE + el;
    if (el >= chunkE || e >= E) return;
    const int* rows   = (s < 4) ? rows1 : rows2;
    const size_t idx  = (size_t)(s & 3) * E + e;
    const int row = rows[idx];
    if (row < lo || row >= hi) return;
    const int* cols   = (s < 4) ? cols1 : cols2;
    const float* vals = (s < 4) ? vals1 : vals2;
    const int pos = base3[((size_t)(s * CCH + c)) * N + row]
                  + (int)rank[(size_t)s * E + e];
    cv[pos] = make_int2(cols[idx], __float_as_int(vals[idx]));
}

// ---------------- W prep: bf16 B-fragments, layout [j][nt][ks][lane][8]
__global__ __launch_bounds__(256) void k_wprep(
    const float* __restrict__ W, short* __restrict__ wb, int d_in)
{
    const int KS  = d_in >> 5;
    const int tid = blockIdx.x * 256 + threadIdx.x;
    if (tid >= 2 * 8 * KS * 64) return;
    const int l    = tid & 63;
    const int rest = tid >> 6;
    const int ks   = rest % KS;
    const int tt   = rest / KS;
    const int t    = tt & 7;
    const int j    = tt >> 3;
    const int r    = ((t >> 2) << 1) + j;
    const int c    = ((t & 3) << 4) + (l & 15);
    const int k0   = (ks << 5) + ((l >> 4) << 3);
    s16x8 v;
#pragma unroll
    for (int e = 0; e < 8; ++e)
        v[e] = (short)f2bf(W[((size_t)r * d_in + k0 + e) * 64 + c]);
    *reinterpret_cast<s16x8*>(wb + (size_t)tid * 8) = v;
}

// ---------------- MFMA dense transform -> XWs[q=(j,i,half)][N][32] bf16
// MODE 0: A = H (raw). MODE 1: A = relu(H). MODE 2: A = relu(H + bf16 P).
template<int KS, int MODE>
__global__ __launch_bounds__(256) void k_gemm(
    const float* __restrict__ H,              // [2, N, d_in]
    const unsigned short* __restrict__ P,     // [2, N, 64] bf16 (MODE 2)
    const short* __restrict__ wb,             // [2][8][KS][64][8]
    unsigned short* __restrict__ XWs,         // [8][N][32]
    int N)
{
    __shared__ __hip_bfloat16 lds_o[64][136];
    const int d_in = KS * 32;
    const int j    = blockIdx.y;
    const int wv   = threadIdx.x >> 6;
    const int lane = threadIdx.x & 63;
    const int row0 = blockIdx.x * 64;

    const int arow = row0 + wv * 16 + (lane & 15);
    const int rc   = (arow < N) ? arow : (N - 1);
    const int koff = (lane >> 4) << 3;
    const float* Hb = H + (size_t)j * N * d_in + (size_t)rc * d_in + koff;
    const unsigned short* Pb = P + ((size_t)j * N + rc) * DOUT + koff;

    s16x8 a[KS];
#pragma unroll
    for (int ks = 0; ks < KS; ++ks) {
        union { float4 v; float f[4]; } f0, f1;
        f0.v = *reinterpret_cast<const float4*>(Hb + ks * 32);
        f1.v = *reinterpret_cast<const float4*>(Hb + ks * 32 + 4);
        float pv[8];
        if (MODE == 2) {
            const uint4 pu = *reinterpret_cast<const uint4*>(Pb + ks * 32);
            pv[0] = bf2f_lo(pu.x); pv[1] = bf2f_hi(pu.x);
            pv[2] = bf2f_lo(pu.y); pv[3] = bf2f_hi(pu.y);
            pv[4] = bf2f_lo(pu.z); pv[5] = bf2f_hi(pu.z);
            pv[6] = bf2f_lo(pu.w); pv[7] = bf2f_hi(pu.w);
        }
        s16x8 t;
#pragma unroll
        for (int e = 0; e < 4; ++e) {
            float v0 = f0.f[e], v1 = f1.f[e];
            if (MODE == 2) { v0 += pv[e]; v1 += pv[4 + e]; }
            if (MODE >= 1) { v0 = fmaxf(v0, 0.f); v1 = fmaxf(v1, 0.f); }
            t[e] = (short)f2bf(v0); t[4 + e] = (short)f2bf(v1);
        }
        a[ks] = t;
    }

    f32x4 acc[8];
#pragma unroll
    for (int nt = 0; nt < 8; ++nt) acc[nt] = (f32x4){0.f, 0.f, 0.f, 0.f};

    const short* wbase = wb + ((size_t)j * 8 * KS * 64 + lane) * 8;
#pragma unroll
    for (int ks = 0; ks < KS; ++ks) {
#pragma unroll
        for (int nt = 0; nt < 8; ++nt) {
            const s16x8 b = *reinterpret_cast<const s16x8*>(
                wbase + (size_t)(nt * KS + ks) * 64 * 8);
            acc[nt] = __builtin_amdgcn_mfma_f32_16x16x32_bf16(a[ks], b, acc[nt], 0, 0, 0);
        }
    }

#pragma unroll
    for (int nt = 0; nt < 8; ++nt)
#pragma unroll
        for (int r = 0; r < 4; ++r)
            lds_o[wv * 16 + ((lane >> 4) << 2) + r][nt * 16 + (lane & 15)] =
                __float2bfloat16(acc[nt][r]);
    __syncthreads();

    // repack: g = t&15 -> global cols 8g..8g+7 -> slice q=(j, i=g>>3, half=(g>>2)&1)
    const int t = threadIdx.x;
#pragma unroll
    for (int p = 0; p < 4; ++p) {
        const int r = p * 16 + (t >> 4);
        const int n = row0 + r;
        if (n < N) {
            const int g = t & 15;
            const int q = (j << 2) | ((g >> 3) << 1) | ((g >> 2) & 1);
            const uint4 v = *reinterpret_cast<const uint4*>(&lds_o[r][g * 8]);
            *reinterpret_cast<uint4*>(
                XWs + ((size_t)q * N + n) * 32 + (g & 3) * 8) = v;
        }
    }
}

// ---------------- XCD-sliced SpMM: q = bid&7 -> slice (js,i,half), 3.2MB/XCD.
// slot = lane>>3 (8 edges/iter), ol = lane&7 (uint2 = 4 bf16 cols/lane).
// js=0 -> out f32; js=1 -> P bf16. Sum deferred to next gemm load / k_addP.
__global__ __launch_bounds__(256) void k_spmm_split(
    const int* __restrict__ row_ptr, int set4,
    const int2* __restrict__ cv,
    const unsigned short* __restrict__ XWs,   // [8][N][32]
    float* __restrict__ outF,                 // [2, N, 64]
    unsigned short* __restrict__ Pb,          // [2, N, 64] bf16
    int N)
{
    const int bid  = blockIdx.x;
    const int q    = bid & 7;
    const int wv   = threadIdx.x >> 6;
    const int n    = (bid >> 3) * 4 + wv;
    if (n >= N) return;
    const int lane = threadIdx.x & 63;
    const int slot = lane >> 3;
    const int ol   = lane & 7;
    const int js   = q >> 2, i = (q >> 1) & 1, half = q & 1;

    const int* rp = row_ptr + (size_t)(set4 + 2 * i + js) * N;
    const int s = rp[n];
    const int e = rp[n + 1];

    const unsigned short* xw = XWs + ((size_t)q * N) * 32 + ol * 4;

    float a0 = 0.f, a1 = 0.f, a2 = 0.f, a3 = 0.f;
    for (int t0 = s; t0 < e; t0 += 8) {
        const int t  = t0 + slot;
        const bool v = (t < e);
        const int tc = v ? t : (e - 1);
        const int2 p = cv[tc];
        const float val = v ? __int_as_float(p.y) : 0.f;
        const uint2 u = *reinterpret_cast<const uint2*>(xw + ((size_t)p.x << 5));
        a0 = fmaf(val, bf2f_lo(u.x), a0);
        a1 = fmaf(val, bf2f_hi(u.x), a1);
        a2 = fmaf(val, bf2f_lo(u.y), a2);
        a3 = fmaf(val, bf2f_hi(u.y), a3);
    }

#pragma unroll
    for (int m = 8; m < 64; m <<= 1) {
        a0 += __shfl_xor(a0, m, 64);
        a1 += __shfl_xor(a1, m, 64);
        a2 += __shfl_xor(a2, m, 64);
        a3 += __shfl_xor(a3, m, 64);
    }

    if (slot == 0) {
        const size_t off = ((size_t)i * N + n) * DOUT + half * 32 + ol * 4;
        if (js == 0) {
            *reinterpret_cast<float4*>(outF + off) = make_float4(a0, a1, a2, a3);
        } else {
            uint2 pk;
            pk.x = (unsigned)f2bf(a0) | ((unsigned)f2bf(a1) << 16);
            pk.y = (unsigned)f2bf(a2) | ((unsigned)f2bf(a3) << 16);
            *reinterpret_cast<uint2*>(Pb + off) = pk;
        }
    }
}

// ---------------- final: out += P (bf16), layer 4 only
__global__ __launch_bounds__(256) void k_addP(
    float* __restrict__ outF, const unsigned short* __restrict__ Pb, int total4)
{
    const int t = blockIdx.x * 256 + threadIdx.x;
    if (t >= total4) return;
    const uint2 pu = *reinterpret_cast<const uint2*>(Pb + (size_t)t * 4);
    float4 o = *reinterpret_cast<const float4*>(outF + (size_t)t * 4);
    o.x += bf2f_lo(pu.x); o.y += bf2f_hi(pu.x);
    o.z += bf2f_lo(pu.y); o.w += bf2f_hi(pu.y);
    *reinterpret_cast<float4*>(outF + (size_t)t * 4) = o;
}

// ---------------- fallback SpMM (small ws): whole row per wave, slice layout
__global__ __launch_bounds__(256) void k_spmm_whole(
    const int* __restrict__ row_ptr, int set4,
    const int2* __restrict__ cv,
    const unsigned short* __restrict__ XWs,   // [8][N][32]
    float* __restrict__ outF,                 // [2, N, 64]
    int N)
{
    const int i    = blockIdx.y;
    const int wv   = threadIdx.x >> 6;
    const int n    = blockIdx.x * 4 + wv;
    if (n >= N) return;
    const int lane = threadIdx.x & 63;
    const int slot = lane >> 3;
    const int ol   = lane & 7;

    float acc[8];
#pragma unroll
    for (int k = 0; k < 8; ++k) acc[k] = 0.f;

#pragma unroll
    for (int js = 0; js < 2; ++js) {
        const int* rp = row_ptr + (size_t)(set4 + 2 * i + js) * N;
        const int s = rp[n];
        const int e = rp[n + 1];
        const int q = (js << 2) | (i << 1) | (ol >> 2);
        const unsigned short* xw = XWs + ((size_t)q * N) * 32 + (ol & 3) * 8;

        for (int t0 = s; t0 < e; t0 += 8) {
            const int t  = t0 + slot;
            const bool v = (t < e);
            const int tc = v ? t : (e - 1);
            const int2 p = cv[tc];
            const float val = v ? __int_as_float(p.y) : 0.f;
            const uint4 u = *reinterpret_cast<const uint4*>(xw + ((size_t)p.x << 5));
            acc[0] = fmaf(val, bf2f_lo(u.x), acc[0]);
            acc[1] = fmaf(val, bf2f_hi(u.x), acc[1]);
            acc[2] = fmaf(val, bf2f_lo(u.y), acc[2]);
            acc[3] = fmaf(val, bf2f_hi(u.y), acc[3]);
            acc[4] = fmaf(val, bf2f_lo(u.z), acc[4]);
            acc[5] = fmaf(val, bf2f_hi(u.z), acc[5]);
            acc[6] = fmaf(val, bf2f_lo(u.w), acc[6]);
            acc[7] = fmaf(val, bf2f_hi(u.w), acc[7]);
        }
    }

#pragma unroll
    for (int m = 8; m < 64; m <<= 1) {
#pragma unroll
        for (int k = 0; k < 8; ++k) acc[k] += __shfl_xor(acc[k], m, 64);
    }

    if (slot == 0) {
        float* op = outF + ((size_t)i * N + n) * DOUT + ol * 8;
        *reinterpret_cast<float4*>(op)     = make_float4(acc[0], acc[1], acc[2], acc[3]);
        *reinterpret_cast<float4*>(op + 4) = make_float4(acc[4], acc[5], acc[6], acc[7]);
    }
}

extern "C" void kernel_launch(void* const* d_in, const int* in_sizes, int n_in,
                              void* d_out, int out_size, void* d_ws, size_t ws_size,
                              hipStream_t stream) {
    const float* feat      = (const float*)d_in[0];
    const int*   adj1_rows = (const int*)  d_in[1];
    const int*   adj1_cols = (const int*)  d_in[2];
    const float* adj1_vals = (const float*)d_in[3];
    const int*   adj2_rows = (const int*)  d_in[4];
    const int*   adj2_cols = (const int*)  d_in[5];
    const float* adj2_vals = (const float*)d_in[6];
    const float* W1        = (const float*)d_in[7];
    const float* W2        = (const float*)d_in[8];
    const float* W3        = (const float*)d_in[9];
    const float* W4        = (const float*)d_in[10];

    const int E = in_sizes[1] / 4;              // 500000
    const int F = in_sizes[7] / (4 * DOUT);     // 128
    const int N = in_sizes[0] / (2 * F);        // 50000
    const int M = 8 * N;
    const int nb1 = (M + 255) / 256;
    const int nw  = (N + WBINS - 1) / WBINS;
    const int chunkE = (E + CCH - 1) / CCH;

    auto align256 = [](size_t x) { return (x + 255) & ~(size_t)255; };

    const size_t cv_b  = align256((size_t)8 * E * sizeof(int2));                   // 32 MB
    const size_t rp_b  = align256(((size_t)M + 8) * sizeof(int));                  // 1.6 MB
    const size_t xw_b  = align256((size_t)8 * N * 32 * sizeof(unsigned short));    // 25.6 MB
    const size_t ha_b  = align256((size_t)2 * N * DOUT * sizeof(float));           // 25.6 MB
    const size_t wb_b  = align256(65536) + 3 * align256(32768);                    // 160 KB
    const size_t p_b   = align256((size_t)2 * N * DOUT * sizeof(unsigned short));  // 12.8 MB

    const int big = (ws_size >= cv_b + rp_b + xw_b + ha_b + wb_b + p_b) ? 1 : 0;

    char* w = (char*)d_ws;
    int2* cv      = (int2*)w;  w += cv_b;
    int*  row_ptr = (int*)w;   w += rp_b;
    unsigned short* XWs = (unsigned short*)w;
    int*  cnt3    = (int*)w;   w += xw_b;                 // build-phase alias
    float* Ha     = (float*)w; w += ha_b;
    unsigned short* rank = (unsigned short*)Ha;           // build-phase alias
    int*  cnt     = (int*)((char*)Ha + align256((size_t)8 * E * sizeof(unsigned short)));
    int*  partials= (int*)((char*)cnt + align256((size_t)M * sizeof(int)));
    short* wb1    = (short*)w; w += align256(65536);
    short* wb2    = (short*)w; w += align256(32768);
    short* wb3    = (short*)w; w += align256(32768);
    short* wb4    = (short*)w; w += align256(32768);
    unsigned short* P = (unsigned short*)w;               // big path only
    float* out    = (float*)d_out;

    // ---- W prep
    k_wprep<<<16, 256, 0, stream>>>(W1, wb1, F);
    k_wprep<<<8, 256, 0, stream>>>(W2, wb2, DOUT);
    k_wprep<<<8, 256, 0, stream>>>(W3, wb3, DOUT);
    k_wprep<<<8, 256, 0, stream>>>(W4, wb4, DOUT);

    // ---- build CSR (segments 0..3 = adj1, 4..7 = adj2), no global atomics
    k_build<<<dim3(nw, 8, CCH), 1024, 0, stream>>>(adj1_rows, adj2_rows, E, chunkE, N, cnt3, rank);
    k_rowsum<<<dim3((N + 255) / 256, 8), 256, 0, stream>>>(cnt3, cnt, N);
    k_scan1<<<nb1, 256, 0, stream>>>(cnt, M, row_ptr, partials);
    k_scan2<<<1, 256, 0, stream>>>(partials, nb1);
    k_scan3<<<nb1, 256, 0, stream>>>(row_ptr, partials, M, 8 * E);
    k_base<<<dim3((N + 255) / 256, 8, CCH), 256, 0, stream>>>(cnt3, row_ptr, N);
    k_fill<<<dim3(8, (chunkE + 255) / 256, CCH * nw), 256, 0, stream>>>(
        adj1_rows, adj1_cols, adj1_vals, adj2_rows, adj2_cols, adj2_vals,
        E, chunkE, N, cnt3, rank, cv);

    const dim3 ggrid((N + 63) / 64, 2);
    const int  sblocks_split = 8 * ((N + 3) / 4);
    const dim3 sgrid_whole((N + 3) / 4, 2);

    // MODE per layer: L1 raw; L2-4 big: relu(H+P); L2-4 small: relu(H)
    auto gemmL = [&](const float* Hin, int mode, int ks, const short* wbl) {
        if (ks == 4) {
            k_gemm<4, 0><<<ggrid, 256, 0, stream>>>(Hin, P, wbl, XWs, N);
        } else if (mode == 2) {
            k_gemm<2, 2><<<ggrid, 256, 0, stream>>>(Hin, P, wbl, XWs, N);
        } else {
            k_gemm<2, 1><<<ggrid, 256, 0, stream>>>(Hin, P, wbl, XWs, N);
        }
    };

    if (big) {
        gemmL(feat, 0, 4, wb1);
        k_spmm_split<<<sblocks_split, 256, 0, stream>>>(row_ptr, 0, cv, XWs, Ha, P, N);
        gemmL(Ha, 2, 2, wb2);
        k_spmm_split<<<sblocks_split, 256, 0, stream>>>(row_ptr, 0, cv, XWs, out, P, N);
        gemmL(out, 2, 2, wb3);
        k_spmm_split<<<sblocks_split, 256, 0, stream>>>(row_ptr, 4, cv, XWs, Ha, P, N);
        gemmL(Ha, 2, 2, wb4);
        k_spmm_split<<<sblocks_split, 256, 0, stream>>>(row_ptr, 4, cv, XWs, out, P, N);
        k_addP<<<(2 * N * DOUT / 4 + 255) / 256, 256, 0, stream>>>(out, P, 2 * N * DOUT / 4);
    } else {
        gemmL(feat, 0, 4, wb1);
        k_spmm_whole<<<sgrid_whole, 256, 0, stream>>>(row_ptr, 0, cv, XWs, Ha, N);
        gemmL(Ha, 1, 2, wb2);
        k_spmm_whole<<<sgrid_whole, 256, 0, stream>>>(row_ptr, 0, cv, XWs, out, N);
        gemmL(out, 1, 2, wb3);
        k_spmm_whole<<<sgrid_whole, 256, 0, stream>>>(row_ptr, 4, cv, XWs, Ha, N);
        gemmL(Ha, 1, 2, wb4);
        k_spmm_whole<<<sgrid_whole, 256, 0, stream>>>(row_ptr, 4, cv, XWs, out, N);
    }
}

// Round 14
// 361.684 us; speedup vs baseline: 1.6951x; 1.6951x over previous
//
#include <hip/hip_runtime.h>
#include <hip/hip_bf16.h>

// Multi-relational GCN, 4 layers. Round 14 (= round 12 + spmm ILP):
//  - spmm: whole-row waves (r11/r12 structure), edge loop unrolled x2 with
//    independent register sets (2 cv loads + 2 uint4 gathers in flight,
//    dual accumulator banks) to hide L3 gather latency
//  - row-windowed fill, MFMA gemm, chunked build identical to round 12
// relation r = 2*i + j: dst type i = r>>1, src type j = r&1.
// Segments 0..3 = adj1 (layers 1-2), 4..7 = adj2 (layers 3-4).

#define DOUT 64
#define WBINS 12800   // 51.2 KB LDS histogram window / fill row-window
#define CCH   8       // edge chunks

typedef __attribute__((ext_vector_type(8))) short s16x8;
typedef __attribute__((ext_vector_type(4))) float f32x4;

__device__ __forceinline__ float bf2f_lo(unsigned u) {
    return __uint_as_float(u << 16);
}
__device__ __forceinline__ float bf2f_hi(unsigned u) {
    return __uint_as_float(u & 0xffff0000u);
}
__device__ __forceinline__ short f2bf(float x) {
    union { __hip_bfloat16 h; short s; } u;
    u.h = __float2bfloat16(x);
    return u.s;
}

// ---------------- build: per-(seg,window,chunk) LDS histogram + u16 rank
__global__ __launch_bounds__(1024) void k_build(
    const int* __restrict__ rows1, const int* __restrict__ rows2,
    int E, int chunkE, int N, int* __restrict__ cnt3, unsigned short* __restrict__ rank)
{
    __shared__ int bins[WBINS];
    const int w = blockIdx.x;
    const int s = blockIdx.y;
    const int c = blockIdx.z;
    const int lo = w * WBINS;
    const int hi = min(N, lo + WBINS);
    const int nb = hi - lo;
    if (nb <= 0) return;
    const int* rows = (s < 4) ? rows1 : rows2;
    const size_t base = (size_t)(s & 3) * E;
    const int e0 = c * chunkE;
    const int e1 = min(E, e0 + chunkE);

    for (int b = threadIdx.x; b < nb; b += 1024) bins[b] = 0;
    __syncthreads();

    for (int e = e0 + threadIdx.x; e < e1; e += 1024) {
        const int row = rows[base + e];
        if (row >= lo && row < hi) {
            const int r = atomicAdd(&bins[row - lo], 1);
            rank[(size_t)s * E + e] = (unsigned short)r;
        }
    }
    __syncthreads();

    for (int b = threadIdx.x; b < nb; b += 1024)
        cnt3[((size_t)(s * CCH + c)) * N + lo + b] = bins[b];
}

// ---------------- per-row: exclusive prefix over chunk counts (in place) + total
__global__ __launch_bounds__(256) void k_rowsum(
    int* __restrict__ cnt3, int* __restrict__ cnt, int N)
{
    const int row = blockIdx.x * 256 + threadIdx.x;
    const int s   = blockIdx.y;
    if (row >= N) return;
    int sum = 0;
#pragma unroll
    for (int c = 0; c < CCH; ++c) {
        const size_t idx = ((size_t)(s * CCH + c)) * N + row;
        const int v = cnt3[idx];
        cnt3[idx] = sum;
        sum += v;
    }
    cnt[(size_t)s * N + row] = sum;
}

// ---------------- exclusive scan, 3-kernel
__global__ __launch_bounds__(256) void k_scan1(
    const int* __restrict__ cnt, int M, int* __restrict__ out, int* __restrict__ partials)
{
    __shared__ int sm[256];
    const int i = blockIdx.x * 256 + threadIdx.x;
    const int x = (i < M) ? cnt[i] : 0;
    sm[threadIdx.x] = x;
    __syncthreads();
    for (int off = 1; off < 256; off <<= 1) {
        int t = (threadIdx.x >= off) ? sm[threadIdx.x - off] : 0;
        __syncthreads();
        sm[threadIdx.x] += t;
        __syncthreads();
    }
    if (i < M) out[i] = sm[threadIdx.x] - x;
    if (threadIdx.x == 255) partials[blockIdx.x] = sm[255];
}

__global__ __launch_bounds__(256) void k_scan2(int* __restrict__ partials, int nb)
{
    __shared__ int sm[256];
    __shared__ int carry_s;
    if (threadIdx.x == 0) carry_s = 0;
    __syncthreads();
    for (int base = 0; base < nb; base += 256) {
        const int i = base + threadIdx.x;
        const int x = (i < nb) ? partials[i] : 0;
        sm[threadIdx.x] = x;
        __syncthreads();
        for (int off = 1; off < 256; off <<= 1) {
            int t = (threadIdx.x >= off) ? sm[threadIdx.x - off] : 0;
            __syncthreads();
            sm[threadIdx.x] += t;
            __syncthreads();
        }
        const int carry = carry_s;
        const int incl  = sm[threadIdx.x];
        __syncthreads();
        if (i < nb) partials[i] = incl - x + carry;
        if (threadIdx.x == 255) carry_s = carry + incl;
        __syncthreads();
    }
}

__global__ __launch_bounds__(256) void k_scan3(
    int* __restrict__ row_ptr, const int* __restrict__ partials, int M, int total)
{
    const int i = blockIdx.x * 256 + threadIdx.x;
    if (i < M) row_ptr[i] += partials[blockIdx.x];
    if (i == 0) row_ptr[M] = total;
}

// ---------------- base fusion: cnt3[(s,c),row] += row_ptr[s,row]  (in place)
__global__ __launch_bounds__(256) void k_base(
    int* __restrict__ cnt3, const int* __restrict__ row_ptr, int N)
{
    const int row = blockIdx.x * 256 + threadIdx.x;
    const int s   = blockIdx.y;
    const int c   = blockIdx.z;
    if (row >= N) return;
    cnt3[((size_t)(s * CCH + c)) * N + row] += row_ptr[(size_t)s * N + row];
}

// ---------------- row-windowed atomic-free CSR fill: pos = base3 + rank
__global__ __launch_bounds__(256) void k_fill(
    const int* __restrict__ rows1, const int* __restrict__ cols1, const float* __restrict__ vals1,
    const int* __restrict__ rows2, const int* __restrict__ cols2, const float* __restrict__ vals2,
    int E, int chunkE, int N,
    const int* __restrict__ base3, const unsigned short* __restrict__ rank,
    int2* __restrict__ cv)
{
    const int s  = blockIdx.x;
    const int z  = blockIdx.z;
    const int c  = z % CCH;
    const int wf = z / CCH;
    const int lo = wf * WBINS;
    const int hi = min(N, lo + WBINS);
    const int el = blockIdx.y * 256 + threadIdx.x;
    const int e  = c * chunkE + el;
    if (el >= chunkE || e >= E) return;
    const int* rows   = (s < 4) ? rows1 : rows2;
    const size_t idx  = (size_t)(s & 3) * E + e;
    const int row = rows[idx];
    if (row < lo || row >= hi) return;
    const int* cols   = (s < 4) ? cols1 : cols2;
    const float* vals = (s < 4) ? vals1 : vals2;
    const int pos = base3[((size_t)(s * CCH + c)) * N + row]
                  + (int)rank[(size_t)s * E + e];
    cv[pos] = make_int2(cols[idx], __float_as_int(vals[idx]));
}

// ---------------- W prep: bf16 B-fragments, layout [j][nt][ks][lane][8]
__global__ __launch_bounds__(256) void k_wprep(
    const float* __restrict__ W, short* __restrict__ wb, int d_in)
{
    const int KS  = d_in >> 5;
    const int tid = blockIdx.x * 256 + threadIdx.x;
    if (tid >= 2 * 8 * KS * 64) return;
    const int l    = tid & 63;
    const int rest = tid >> 6;
    const int ks   = rest % KS;
    const int tt   = rest / KS;
    const int t    = tt & 7;
    const int j    = tt >> 3;
    const int r    = ((t >> 2) << 1) + j;
    const int c    = ((t & 3) << 4) + (l & 15);
    const int k0   = (ks << 5) + ((l >> 4) << 3);
    s16x8 v;
#pragma unroll
    for (int e = 0; e < 8; ++e)
        v[e] = f2bf(W[((size_t)r * d_in + k0 + e) * 64 + c]);
    *reinterpret_cast<s16x8*>(wb + (size_t)tid * 8) = v;
}

// ---------------- MFMA dense transform -> XW[j][i][N][64] bf16
template<int KS>
__global__ __launch_bounds__(256) void k_gemm(
    const float* __restrict__ H,           // [2, N, d_in]
    const short* __restrict__ wb,          // [2][8][KS][64][8] bf16 bits
    __hip_bfloat16* __restrict__ XW,       // [2][2][N][64]
    int N)
{
    __shared__ __hip_bfloat16 lds_o[64][136];
    const int d_in = KS * 32;
    const int j    = blockIdx.y;
    const int wv   = threadIdx.x >> 6;
    const int lane = threadIdx.x & 63;
    const int row0 = blockIdx.x * 64;

    const int arow = row0 + wv * 16 + (lane & 15);
    const int rc   = (arow < N) ? arow : (N - 1);
    const float* Hb = H + (size_t)j * N * d_in + (size_t)rc * d_in + ((lane >> 4) << 3);

    s16x8 a[KS];
#pragma unroll
    for (int ks = 0; ks < KS; ++ks) {
        union { float4 v; float f[4]; } f0, f1;
        f0.v = *reinterpret_cast<const float4*>(Hb + ks * 32);
        f1.v = *reinterpret_cast<const float4*>(Hb + ks * 32 + 4);
        s16x8 t;
#pragma unroll
        for (int e = 0; e < 4; ++e) { t[e] = f2bf(f0.f[e]); t[4 + e] = f2bf(f1.f[e]); }
        a[ks] = t;
    }

    f32x4 acc[8];
#pragma unroll
    for (int nt = 0; nt < 8; ++nt) acc[nt] = (f32x4){0.f, 0.f, 0.f, 0.f};

    const short* wbase = wb + ((size_t)j * 8 * KS * 64 + lane) * 8;
#pragma unroll
    for (int ks = 0; ks < KS; ++ks) {
#pragma unroll
        for (int nt = 0; nt < 8; ++nt) {
            const s16x8 b = *reinterpret_cast<const s16x8*>(
                wbase + (size_t)(nt * KS + ks) * 64 * 8);
            acc[nt] = __builtin_amdgcn_mfma_f32_16x16x32_bf16(a[ks], b, acc[nt], 0, 0, 0);
        }
    }

    // C/D layout: col = lane&15, row = (lane>>4)*4 + r
#pragma unroll
    for (int nt = 0; nt < 8; ++nt)
#pragma unroll
        for (int r = 0; r < 4; ++r)
            lds_o[wv * 16 + ((lane >> 4) << 2) + r][nt * 16 + (lane & 15)] =
                __float2bfloat16(acc[nt][r]);
    __syncthreads();

    // repack: thread t -> row r = p*16 + (t>>4); 16B group g = t&15:
    // i = g>>3, col-octet c = (g&7)*8  ->  XW[(j*2+i)][n][c..c+7]
    const int t = threadIdx.x;
#pragma unroll
    for (int p = 0; p < 4; ++p) {
        const int r = p * 16 + (t >> 4);
        const int n = row0 + r;
        if (n < N) {
            const int g = t & 15;
            const uint4 v = *reinterpret_cast<const uint4*>(&lds_o[r][g * 8]);
            *reinterpret_cast<uint4*>(
                (unsigned short*)XW + ((size_t)(j * 2 + (g >> 3)) * N + n) * 64 + (g & 7) * 8) = v;
        }
    }
}

// ---------------- SpMM: ONE wave per dst row; both relations accumulated.
// slot = lane>>3 (8 edges), ol = lane&7 (col-octet uint4 = 8 bf16 cols).
// Edge loop unrolled x2 with independent register sets / dual acc banks
// so two cv loads + two 128B gathers are in flight per wave.
template<int RELU>
__global__ __launch_bounds__(256) void k_spmm(
    const int* __restrict__ row_ptr, int set4,
    const int2* __restrict__ cv,
    const unsigned short* __restrict__ XW,    // bf16 [2][2][N][64]
    float* __restrict__ out,                  // [2, N, 64]
    int N)
{
    const int i    = blockIdx.y;
    const int wv   = threadIdx.x >> 6;
    const int n    = blockIdx.x * 4 + wv;
    if (n >= N) return;
    const int lane = threadIdx.x & 63;
    const int slot = lane >> 3;
    const int ol   = lane & 7;

    float accA[8], accB[8];
#pragma unroll
    for (int k = 0; k < 8; ++k) { accA[k] = 0.f; accB[k] = 0.f; }

#pragma unroll
    for (int js = 0; js < 2; ++js) {
        const int seg = set4 + 2 * i + js;
        const int* rp = row_ptr + (size_t)seg * N;
        const int s = rp[n];
        const int e = rp[n + 1];
        const unsigned short* xw = XW + ((size_t)(js * 2 + i) * N) * 64 + ol * 8;

        for (int t0 = s; t0 < e; t0 += 16) {
            const int ta = t0 + slot;
            const int tb = t0 + 8 + slot;
            const bool va = (ta < e);
            const bool vb = (tb < e);
            const int tca = va ? ta : (e - 1);
            const int tcb = vb ? tb : (e - 1);
            const int2 pa = cv[tca];
            const int2 pb = cv[tcb];
            const float valA = va ? __int_as_float(pa.y) : 0.f;
            const float valB = vb ? __int_as_float(pb.y) : 0.f;
            const uint4 ua = *reinterpret_cast<const uint4*>(xw + ((size_t)pa.x << 6));
            const uint4 ub = *reinterpret_cast<const uint4*>(xw + ((size_t)pb.x << 6));
            accA[0] = fmaf(valA, bf2f_lo(ua.x), accA[0]);
            accA[1] = fmaf(valA, bf2f_hi(ua.x), accA[1]);
            accA[2] = fmaf(valA, bf2f_lo(ua.y), accA[2]);
            accA[3] = fmaf(valA, bf2f_hi(ua.y), accA[3]);
            accA[4] = fmaf(valA, bf2f_lo(ua.z), accA[4]);
            accA[5] = fmaf(valA, bf2f_hi(ua.z), accA[5]);
            accA[6] = fmaf(valA, bf2f_lo(ua.w), accA[6]);
            accA[7] = fmaf(valA, bf2f_hi(ua.w), accA[7]);
            accB[0] = fmaf(valB, bf2f_lo(ub.x), accB[0]);
            accB[1] = fmaf(valB, bf2f_hi(ub.x), accB[1]);
            accB[2] = fmaf(valB, bf2f_lo(ub.y), accB[2]);
            accB[3] = fmaf(valB, bf2f_hi(ub.y), accB[3]);
            accB[4] = fmaf(valB, bf2f_lo(ub.z), accB[4]);
            accB[5] = fmaf(valB, bf2f_hi(ub.z), accB[5]);
            accB[6] = fmaf(valB, bf2f_lo(ub.w), accB[6]);
            accB[7] = fmaf(valB, bf2f_hi(ub.w), accB[7]);
        }
    }

    float acc[8];
#pragma unroll
    for (int k = 0; k < 8; ++k) acc[k] = accA[k] + accB[k];

    // reduce across the 8 slots (lanes ol, ol+8, ..., ol+56)
#pragma unroll
    for (int m = 8; m < 64; m <<= 1) {
#pragma unroll
        for (int k = 0; k < 8; ++k) acc[k] += __shfl_xor(acc[k], m, 64);
    }

    if (slot == 0) {
        if (RELU) {
#pragma unroll
            for (int k = 0; k < 8; ++k) acc[k] = fmaxf(acc[k], 0.f);
        }
        float* op = out + ((size_t)i * N + n) * DOUT + ol * 8;
        *reinterpret_cast<float4*>(op)     = make_float4(acc[0], acc[1], acc[2], acc[3]);
        *reinterpret_cast<float4*>(op + 4) = make_float4(acc[4], acc[5], acc[6], acc[7]);
    }
}

extern "C" void kernel_launch(void* const* d_in, const int* in_sizes, int n_in,
                              void* d_out, int out_size, void* d_ws, size_t ws_size,
                              hipStream_t stream) {
    const float* feat      = (const float*)d_in[0];
    const int*   adj1_rows = (const int*)  d_in[1];
    const int*   adj1_cols = (const int*)  d_in[2];
    const float* adj1_vals = (const float*)d_in[3];
    const int*   adj2_rows = (const int*)  d_in[4];
    const int*   adj2_cols = (const int*)  d_in[5];
    const float* adj2_vals = (const float*)d_in[6];
    const float* W1        = (const float*)d_in[7];
    const float* W2        = (const float*)d_in[8];
    const float* W3        = (const float*)d_in[9];
    const float* W4        = (const float*)d_in[10];

    const int E = in_sizes[1] / 4;              // 500000
    const int F = in_sizes[7] / (4 * DOUT);     // 128
    const int N = in_sizes[0] / (2 * F);        // 50000
    const int M = 8 * N;
    const int nb1 = (M + 255) / 256;
    const int nw  = (N + WBINS - 1) / WBINS;
    const int chunkE = (E + CCH - 1) / CCH;

    auto align256 = [](size_t x) { return (x + 255) & ~(size_t)255; };

    const size_t cv_b   = align256((size_t)8 * E * sizeof(int2));        // 32 MB
    const size_t rp_b   = align256(((size_t)M + 8) * sizeof(int));       // 1.6 MB
    const size_t xw_b   = align256((size_t)2 * 2 * N * 64 * sizeof(__hip_bfloat16)); // 25.6 MB
    const size_t ha_b   = align256((size_t)2 * N * DOUT * sizeof(float));            // 25.6 MB

    char* w = (char*)d_ws;
    int2* cv      = (int2*)w;  w += cv_b;
    int*  row_ptr = (int*)w;   w += rp_b;
    __hip_bfloat16* XW = (__hip_bfloat16*)w;
    int*  cnt3    = (int*)w;   w += xw_b;
    float* Ha     = (float*)w; w += ha_b;
    unsigned short* rank = (unsigned short*)Ha;
    int*  cnt     = (int*)((char*)Ha + align256((size_t)8 * E * sizeof(unsigned short)));
    int*  partials= (int*)((char*)cnt + align256((size_t)M * sizeof(int)));
    short* wb1    = (short*)w;                  // [2][8][4][64][8] = 64 KB
    short* wb2    = wb1 + 32768;                // KS=2 -> 32 KB each
    short* wb3    = wb2 + 16384;
    short* wb4    = wb3 + 16384;
    float* out    = (float*)d_out;

    // ---- W prep (independent of CSR build)
    k_wprep<<<16, 256, 0, stream>>>(W1, wb1, F);
    k_wprep<<<8, 256, 0, stream>>>(W2, wb2, DOUT);
    k_wprep<<<8, 256, 0, stream>>>(W3, wb3, DOUT);
    k_wprep<<<8, 256, 0, stream>>>(W4, wb4, DOUT);

    // ---- build CSR (segments 0..3 = adj1, 4..7 = adj2), no global atomics
    k_build<<<dim3(nw, 8, CCH), 1024, 0, stream>>>(adj1_rows, adj2_rows, E, chunkE, N, cnt3, rank);
    k_rowsum<<<dim3((N + 255) / 256, 8), 256, 0, stream>>>(cnt3, cnt, N);
    k_scan1<<<nb1, 256, 0, stream>>>(cnt, M, row_ptr, partials);
    k_scan2<<<1, 256, 0, stream>>>(partials, nb1);
    k_scan3<<<nb1, 256, 0, stream>>>(row_ptr, partials, M, 8 * E);
    k_base<<<dim3((N + 255) / 256, 8, CCH), 256, 0, stream>>>(cnt3, row_ptr, N);
    k_fill<<<dim3(8, (chunkE + 255) / 256, CCH * nw), 256, 0, stream>>>(
        adj1_rows, adj1_cols, adj1_vals, adj2_rows, adj2_cols, adj2_vals,
        E, chunkE, N, cnt3, rank, cv);

    const dim3 ggrid((N + 63) / 64, 2);
    const dim3 sgrid((N + 3) / 4, 2);

    auto layer = [&](const float* Hin, int d_in, const short* wbl,
                     int set4, float* Hout, int relu_out) {
        if (d_in == 128) k_gemm<4><<<ggrid, 256, 0, stream>>>(Hin, wbl, XW, N);
        else             k_gemm<2><<<ggrid, 256, 0, stream>>>(Hin, wbl, XW, N);
        if (relu_out)
            k_spmm<1><<<sgrid, 256, 0, stream>>>(row_ptr, set4, cv,
                                                 (const unsigned short*)XW, Hout, N);
        else
            k_spmm<0><<<sgrid, 256, 0, stream>>>(row_ptr, set4, cv,
                                                 (const unsigned short*)XW, Hout, N);
    };

    layer(feat, F,    wb1, 0, Ha,  1);   // L1: adj1, relu into L2 input
    layer(Ha,   DOUT, wb2, 0, out, 1);   // L2: adj1, relu into L3 input
    layer(out,  DOUT, wb3, 4, Ha,  1);   // L3: adj2, relu into L4 input
    layer(Ha,   DOUT, wb4, 4, out, 0);   // L4: adj2 (final, no relu)
}